// Round 3
// baseline (295.308 us; speedup 1.0000x reference)
//
#include <hip/hip_runtime.h>
#include <cmath>

// TelephotoInterp: rotate+shift+drift 8.4M particles, CIC-paint z-slab onto
// res x res (2048^2) f32 grid.
//
// Round-9: r7 (occupancy 38->52%) and r8 (batched LDS-atomic chains) both
// left tp_bin at ~90us, VALUBusy ~23%, HBM 17% -> every intra-block pipe
// idle; stall is an external serialized resource. Remaining computable
// suspect: phase-2a gcnt global atomics -- all blocks, barrier-aligned, fire
// 256 atomics/round into the SAME 1KB/XCD and WAIT for the returned cursor;
// same-line atomic RMWs serialize at L2 -> tens of K cycles of queue wait
// per block per round, invisible to VALU/LDS/BW counters.
// Fix: deterministic allocation, zero global atomics in the hot path.
// grec becomes per-(bucket,block) private 32-record arenas ([bucket][block][32],
// 31.5 MB); chunk index = per-bucket LDS counter (single writer, no atomic);
// exact per-block counts written once as u8 (cnts[block][bucket], coalesced).
// Arena overflow (~0.05% of arenas) -> sentinel descriptor -> correct
// scatter_direct fallback. gcnt memset gone. tp_paint scans its bucket's
// 122KB arena region linearly (coalesced) with slot<cnt predicate.

#define TSZ    128        // paint tile edge (cells)
#define NBKT   256        // K1 buckets (= max tiles^2 in fast path, tiles<=16)
#define CAPB   2          // arena chunks per (bucket,block)
#define SLOTS  (CAPB*16)  // 32 records per arena
#define DEPTH  26         // LDS slots per bucket (resid<=15 + Pois(6) burst)
#define NTH    256        // K1 block size
#define NBLK   960        // K1 grid (fits 31.7MB ws arena budget)
#define VEC    4          // particles per thread per chunk
#define NSUB   3          // transform chunks per flush round (rounds=3)
#define DESCMAX 256       // k<=1 per bucket per round -> <=NBKT descriptors
#define SENT   0xFFFFFFFFu

__device__ __forceinline__ float fast_rcp(float x)  { return __builtin_amdgcn_rcpf(x); }
__device__ __forceinline__ float fast_sqrt(float x) { return __builtin_amdgcn_sqrtf(x); }

__device__ __forceinline__ int wrap_idx(int v, int res) {   // generic (fallback path)
    v += (v < 0) ? res : 0;
    v += (v < 0) ? res : 0;
    v += (v < 0) ? res : 0;
    v -= (v >= res) ? res : 0;
    v -= (v >= res) ? res : 0;
    v -= (v >= res) ? res : 0;
    if (v < 0 || v >= res) { v %= res; if (v < 0) v += res; }  // safety net
    return v;
}

__device__ __forceinline__ void scatter_direct(float* __restrict__ out, int res,
                                               int gx0, int gy0, float fx, float fy) {
    int gx1 = gx0 + 1; if (gx1 >= res) gx1 = 0;
    int gy1 = gy0 + 1; if (gy1 >= res) gy1 = 0;
    atomicAdd(&out[gx0 * res + gy0], (1.0f - fx) * (1.0f - fy));
    atomicAdd(&out[gx1 * res + gy0], fx * (1.0f - fy));
    atomicAdd(&out[gx0 * res + gy1], (1.0f - fx) * fy);
    atomicAdd(&out[gx1 * res + gy1], fx * fy);
}

// rec = lx7<<25 | ly7<<18 | qx9<<9 | qy9
__device__ __forceinline__ void rec_decode(unsigned rec, int b, int tiles,
                                           int& gx, int& gy, float& fx, float& fy) {
    int tx = b / tiles, ty = b - tx * tiles;   // rare path only
    gx = (tx << 7) + (int)(rec >> 25);
    gy = (ty << 7) + (int)((rec >> 18) & 127u);
    fx = (float)((rec >> 9) & 511u) * (1.0f / 512.0f);
    fy = (float)(rec & 511u) * (1.0f / 512.0f);
}

// uniforms for the per-particle fast path
struct Uni {
    float m00, m01, m02, m10, m11, m12, m20, m21, m22;
    float ox, oy, oz, shift;
    float r_lo, r_hi, t, gp_t, scale;
    int   resm1, res, tiles;
    bool  inside;
};

// per-particle result (all fields in registers; fully unrolled callers)
struct PR {
    unsigned rec, st;
    int ix0, iy0;
    float fx, fy;
    bool val;
};

// ---------------- K1 per-particle compute (branch-free, no side effects) ----
__device__ __forceinline__ PR tp_compute(
    const Uni& u, unsigned dummy,
    float px, float py, float pz, float vx, float vy, float vz)
{
    float X, Y, Z;
    if (u.inside) {
        X = px; Y = py; Z = pz;
    } else {
        const float qx_ = px - u.ox, qy_ = py - u.oy, qz_ = pz - u.oz;
        float rx = u.m00 * qx_ + u.m01 * qy_ + u.m02 * qz_;
        float ry = u.m10 * qx_ + u.m11 * qy_ + u.m12 * qz_;
        float rz = u.m20 * qx_ + u.m21 * qy_ + u.m22 * qz_ + u.shift;

        const float vrx = u.m00 * vx + u.m01 * vy + u.m02 * vz;
        const float vry = u.m10 * vx + u.m11 * vy + u.m12 * vz;
        const float vrz = u.m20 * vx + u.m21 * vy + u.m22 * vz;

        const float dx = rx - u.ox, dy = ry - u.oy, dz = rz - u.oz;
        const float dist  = fast_sqrt(dx * dx + dy * dy + dz * dz);
        const float a_tgt = fast_rcp(1.0f + dist * (1.0f / 3000.0f));
        const float ac    = fast_sqrt(u.t * a_tgt);
        const float gp_a  = a_tgt * fast_sqrt(a_tgt);          // a^1.5
        const float drift = (gp_a - u.gp_t) * fast_rcp(1.5f * fast_sqrt(ac));

        X = rx + drift * vrx + u.ox;
        Y = ry + drift * vry + u.oy;
        Z = rz + drift * vrz + u.oz;
    }
    PR o;
    o.val = (Z >= u.r_lo && Z < u.r_hi);

    // all of the below is finite/safe even for rejected particles
    const float gx = X * u.scale, gy = Y * u.scale;
    const float fgx = floorf(gx), fgy = floorf(gy);
    o.fx = gx - fgx; o.fy = gy - fgy;
    o.ix0 = ((int)fgx) & u.resm1;   // exact mod for pow2 res
    o.iy0 = ((int)fgy) & u.resm1;
    const unsigned st = (unsigned)((o.ix0 >> 7) * u.tiles + (o.iy0 >> 7));
    o.st = o.val ? st : dummy;      // invalid lanes -> per-lane dummy bucket

    unsigned qx = (unsigned)(o.fx * 512.0f + 0.5f); if (qx > 511u) qx = 511u;
    unsigned qy = (unsigned)(o.fy * 512.0f + 0.5f); if (qy > 511u) qy = 511u;
    o.rec = ((unsigned)(o.ix0 & 127) << 25) | ((unsigned)(o.iy0 & 127) << 18)
          | (qx << 9) | qy;
    return o;
}

__device__ __forceinline__ void tp_finish(
    const Uni& u, const PR& o, unsigned p,
    unsigned* __restrict__ fill, unsigned* __restrict__ buf,
    float* __restrict__ out)
{
    if (!o.val) return;
    if (p < DEPTH) buf[o.st * DEPTH + p] = o.rec;
    else { atomicSub(&fill[o.st], 1u); scatter_direct(out, u.res, o.ix0, o.iy0, o.fx, o.fy); }
}

// legacy branchy path (generic tail only)
__device__ __forceinline__ void tp_process(
    const Uni& u, float px, float py, float pz, float vx, float vy, float vz,
    unsigned* __restrict__ fill, unsigned* __restrict__ buf,
    float* __restrict__ out)
{
    const PR o = tp_compute(u, 0u, px, py, pz, vx, vy, vz);
    if (!o.val) return;
    unsigned p = atomicAdd(&fill[o.st], 1u);
    tp_finish(u, o, p, fill, buf, out);
}

// ---------------- K1: transform + LDS-batched bin ----------------
__global__ __launch_bounds__(NTH) void tp_bin(
    const float* __restrict__ pos, const float* __restrict__ vel,
    const float* __restrict__ rotations, const float* __restrict__ observer,
    const float* __restrict__ r_centers, const float* __restrict__ widths,
    const float* __restrict__ t_p, const float* __restrict__ maxd_p,
    const float* __restrict__ box_p, const int* __restrict__ shell_p,
    const int* __restrict__ ridx_p,
    unsigned char* __restrict__ cnts, unsigned* __restrict__ grec,
    float* __restrict__ out, int res, int tiles, int n, int rounds)
{
    __shared__ unsigned fill[NBKT + 64];   // +64 per-lane dummy buckets
    __shared__ unsigned buf[NBKT * DEPTH];
    __shared__ unsigned descB[DESCMAX];
    __shared__ unsigned descD[DESCMAX];
    __shared__ unsigned char cidA[NBKT];   // chunks emitted per bucket
    __shared__ unsigned ndesc;

    const int tid = threadIdx.x;
    for (int b = tid; b < NBKT + 64; b += NTH) fill[b] = 0;
    if (tid < NBKT) cidA[tid] = 0;
    if (tid == 0) ndesc = 0;

    Uni u;
    {
        const int   shell    = shell_p[0];
        const float r_center = r_centers[shell];
        const float width    = widths[shell];
        const float maxd     = maxd_p[0];
        const float box      = box_p[0];
        u.t      = t_p[0];
        u.inside = (r_center + width * 0.5f) <= maxd;
        int ridx = ridx_p[0] % 47; if (ridx < 0) ridx += 47;
        const float* M = rotations + 9 * ridx;
        u.m00 = M[0]; u.m01 = M[1]; u.m02 = M[2];
        u.m10 = M[3]; u.m11 = M[4]; u.m12 = M[5];
        u.m20 = M[6]; u.m21 = M[7]; u.m22 = M[8];
        u.ox = observer[0]; u.oy = observer[1]; u.oz = observer[2];
        u.shift = floorf(r_center / maxd) * maxd;
        u.r_lo = r_center - width * 0.5f;
        u.r_hi = r_center + width * 0.5f;
        u.gp_t = u.t * sqrtf(u.t);
        u.scale = (float)res / box;
        u.resm1 = res - 1; u.res = res; u.tiles = tiles;
    }

    const unsigned dummy = (unsigned)(NBKT + (tid & 63));
    const float4* __restrict__ pos4 = (const float4*)pos;
    const float4* __restrict__ vel4 = (const float4*)vel;

    __syncthreads();

    for (int r = 0; r < rounds; ++r) {
        // phase 1: NSUB transform chunks, 4 particles each (3+3 float4 loads)
        #pragma unroll 1
        for (int s = 0; s < NSUB; ++s) {
            const int rc = r * NSUB + s;
            const int base = ((rc * NBLK + blockIdx.x) * NTH + tid) * VEC;
            if (base + VEC <= n) {
                const int q = base * 3 / 4;   // float4 index (base*3 divisible by 4)
                const float4 a = pos4[q], b = pos4[q + 1], c = pos4[q + 2];
                PR r0, r1, r2, r3;
                if (u.inside) {
                    r0 = tp_compute(u, dummy, a.x, a.y, a.z, 0, 0, 0);
                    r1 = tp_compute(u, dummy, a.w, b.x, b.y, 0, 0, 0);
                    r2 = tp_compute(u, dummy, b.z, b.w, c.x, 0, 0, 0);
                    r3 = tp_compute(u, dummy, c.y, c.z, c.w, 0, 0, 0);
                } else {
                    const float4 d = vel4[q], e = vel4[q + 1], f = vel4[q + 2];
                    r0 = tp_compute(u, dummy, a.x, a.y, a.z, d.x, d.y, d.z);
                    r1 = tp_compute(u, dummy, a.w, b.x, b.y, d.w, e.x, e.y);
                    r2 = tp_compute(u, dummy, b.z, b.w, c.x, e.z, e.w, f.x);
                    r3 = tp_compute(u, dummy, c.y, c.z, c.w, f.y, f.z, f.w);
                }
                // batched: 4 ds_add_rtn back-to-back, one wait, then finishes
                const unsigned p0 = atomicAdd(&fill[r0.st], 1u);
                const unsigned p1 = atomicAdd(&fill[r1.st], 1u);
                const unsigned p2 = atomicAdd(&fill[r2.st], 1u);
                const unsigned p3 = atomicAdd(&fill[r3.st], 1u);
                tp_finish(u, r0, p0, fill, buf, out);
                tp_finish(u, r1, p1, fill, buf, out);
                tp_finish(u, r2, p2, fill, buf, out);
                tp_finish(u, r3, p3, fill, buf, out);
            } else {
                for (int p = 0; p < VEC; ++p) {
                    const int i = base + p;
                    if (i >= 0 && i < n)
                        tp_process(u, pos[3 * i], pos[3 * i + 1], pos[3 * i + 2],
                                   vel[3 * i], vel[3 * i + 1], vel[3 * i + 2],
                                   fill, buf, out);
                }
            }
        }
        __syncthreads();
        // phase 2a: build flush descriptors (thread b <-> bucket b).
        // Deterministic arena allocation: NO global atomics, only LDS.
        if (tid < NBKT) {
            const unsigned c = fill[tid];
            const unsigned k = c >> 4;
            if (k) {
                unsigned d = atomicAdd(&ndesc, k);
                unsigned cid = cidA[tid];
                for (unsigned g = 0; g < k; ++g) {
                    descB[d + g] = (unsigned)tid | ((g * 16u) << 16);
                    descD[d + g] = (cid < CAPB)
                        ? (unsigned)(((unsigned)tid * NBLK + blockIdx.x) * SLOTS + cid * 16u)
                        : SENT;
                    ++cid;
                }
                cidA[tid] = (unsigned char)cid;
            }
        }
        __syncthreads();
        // phase 2b: cooperative coalesced flush, 16 lanes per descriptor
        const unsigned nd = ndesc;
        for (unsigned did = (unsigned)(tid >> 4); did < nd; did += NTH / 16) {
            const unsigned e = descB[did];
            const unsigned b = e & 0xffffu, so = e >> 16;
            const unsigned rv = buf[b * DEPTH + so + (tid & 15)];
            const unsigned dstb = descD[did];
            if (dstb != SENT) {
                grec[(size_t)dstb + (tid & 15)] = rv;
            } else {  // arena overflow: correct fallback
                int gx0, gy0; float ffx, ffy;
                rec_decode(rv, (int)b, u.tiles, gx0, gy0, ffx, ffy);
                scatter_direct(out, u.res, gx0, gy0, ffx, ffy);
            }
        }
        __syncthreads();
        // phase 2c: compact residues, reset descriptor count
        if (tid < NBKT) {
            const unsigned c = fill[tid];
            const unsigned k = c >> 4;
            if (k) {
                const unsigned resid = c - 16u * k;
                for (unsigned j = 0; j < resid; ++j)
                    buf[tid * DEPTH + j] = buf[tid * DEPTH + 16u * k + j];
                fill[tid] = resid;
            }
        }
        if (tid == 0) ndesc = 0;
        __syncthreads();
    }

    // final flush: drain residues (c <= 15 each) + write exact counts
    if (tid < NBKT) {
        const unsigned c = fill[tid];
        const unsigned cid = cidA[tid];
        const unsigned wc = (cid < CAPB) ? cid : (unsigned)CAPB;
        const bool rw = (c > 0) && (cid < CAPB);
        cnts[(size_t)blockIdx.x * NBKT + tid] = (unsigned char)(16u * wc + (rw ? c : 0u));
        if (c) {
            unsigned d = atomicAdd(&ndesc, 1u);
            descB[d] = (unsigned)tid | (c << 16);
            descD[d] = rw
                ? (unsigned)(((unsigned)tid * NBLK + blockIdx.x) * SLOTS + cid * 16u)
                : SENT;
        }
    }
    __syncthreads();
    const unsigned nd = ndesc;
    for (unsigned did = (unsigned)(tid >> 4); did < nd; did += NTH / 16) {
        const unsigned e = descB[did];
        const unsigned b = e & 0xffffu, c = e >> 16;
        const unsigned lane = (unsigned)(tid & 15);
        if (lane < c) {
            const unsigned rv = buf[b * DEPTH + lane];
            const unsigned dstb = descD[did];
            if (dstb != SENT) {
                grec[(size_t)dstb + lane] = rv;
            } else {
                int gx0, gy0; float ffx, ffy;
                rec_decode(rv, (int)b, u.tiles, gx0, gy0, ffx, ffy);
                scatter_direct(out, u.res, gx0, gy0, ffx, ffy);
            }
        }
    }
}

// ---------------- K2: paint (one 128-tile per block, quad u64 accumulate) ----
// 4 parity-staggered quad grids; a record at (li,lj) hits exactly one quad:
// grid (li&1, lj&1), index (li>>1, lj>>1). u64 = 4x u16 fixed-point (2^-10):
// slot(r,s) at bits 16*(r*2+s) = weight for cell (li+r, lj+s). Exact while
// each cell's weight-sum < 64 (actual max ~12).
// Record read: linear coalesced scan of this bucket's NBLK*SLOTS arena
// region; slot validity via per-block u8 counts preloaded in LDS.
__global__ __launch_bounds__(1024) void tp_paint(
    const unsigned char* __restrict__ cnts, const unsigned* __restrict__ grec,
    float* __restrict__ out, int res, int tiles)
{
    __shared__ unsigned long long quad[4][64 * 64];   // 128 KB
    __shared__ unsigned char cs[NBLK];                // per-source-block counts
    const int b = blockIdx.x;
    const int tx = b / tiles, ty = b - tx * tiles;

    for (int c = threadIdx.x; c < 4 * 64 * 64; c += blockDim.x)
        quad[c >> 12][c & 4095] = 0ull;
    for (int i = threadIdx.x; i < NBLK; i += blockDim.x)
        cs[i] = cnts[(size_t)i * NBKT + b];
    __syncthreads();

    const unsigned* __restrict__ rr = grec + (size_t)b * NBLK * SLOTS;
    const int total = NBLK * SLOTS;
    for (int idx = threadIdx.x; idx < total; idx += blockDim.x) {
        const unsigned p = rr[idx];                    // coalesced stream
        if ((idx & (SLOTS - 1)) < (int)cs[idx >> 5]) { // SLOTS == 32
            const int li = (int)(p >> 25);
            const int lj = (int)((p >> 18) & 127u);
            const unsigned qx = (p >> 9) & 511u;
            const unsigned qy = p & 511u;
            const unsigned ax = 512u - qx, ay = 512u - qy;
            const unsigned long long w00 = (ax * ay + 128u) >> 8;
            const unsigned long long w01 = (ax * qy + 128u) >> 8;
            const unsigned long long w10 = (qx * ay + 128u) >> 8;
            const unsigned long long w11 = (qx * qy + 128u) >> 8;
            const unsigned long long pk = w00 | (w01 << 16) | (w10 << 32) | (w11 << 48);
            const int g = ((li & 1) << 1) | (lj & 1);
            atomicAdd(&quad[g][(li >> 1) * 64 + (lj >> 1)], pk);
        }
    }
    __syncthreads();

    for (int c = threadIdx.x; c < (TSZ + 1) * (TSZ + 1); c += blockDim.x) {
        const int i = c / (TSZ + 1), j = c - i * (TSZ + 1);
        unsigned acc = 0;
        #pragma unroll
        for (int r = 0; r < 2; ++r) {
            const int ii = i - r;
            if (ii < 0 || ii > TSZ - 1) continue;
            #pragma unroll
            for (int s = 0; s < 2; ++s) {
                const int jj = j - s;
                if (jj < 0 || jj > TSZ - 1) continue;
                const int g = ((ii & 1) << 1) | (jj & 1);
                const unsigned long long v = quad[g][(ii >> 1) * 64 + (jj >> 1)];
                acc += (unsigned)((v >> (16 * (r * 2 + s))) & 0xffffull);
            }
        }
        const float val = (float)acc * (1.0f / 1024.0f);
        int gx = tx * TSZ + i; if (gx >= res) gx -= res;
        int gy = ty * TSZ + j; if (gy >= res) gy -= res;
        float* dst = &out[gx * res + gy];
        if (i == 0 || j == 0 || i == TSZ || j == TSZ) {
            if (val != 0.0f) atomicAdd(dst, val);   // halo-shared frame cells
        } else {
            *dst += val;   // exclusive writer; += keeps fallback atomics
        }
    }
}

// ---------------- fallback direct kernel (non-pow2 / odd res / small ws) ----
__global__ __launch_bounds__(256) void tp_direct(
    const float* __restrict__ pos, const float* __restrict__ vel,
    const float* __restrict__ rotations, const float* __restrict__ observer,
    const float* __restrict__ r_centers, const float* __restrict__ widths,
    const float* __restrict__ t_p, const float* __restrict__ maxd_p,
    const float* __restrict__ box_p, const int* __restrict__ shell_p,
    const int* __restrict__ ridx_p, float* __restrict__ out, int res, int n)
{
    int i = blockIdx.x * blockDim.x + threadIdx.x;
    if (i >= n) return;
    const int   shell    = shell_p[0];
    const float r_center = r_centers[shell];
    const float width    = widths[shell];
    const float maxd     = maxd_p[0];
    const float box      = box_p[0];
    const float t        = t_p[0];
    const bool  inside   = (r_center + width * 0.5f) <= maxd;
    int ridx = ridx_p[0] % 47; if (ridx < 0) ridx += 47;

    float px = pos[3 * i], py = pos[3 * i + 1], pz = pos[3 * i + 2];
    float X, Y, Z;
    if (inside) {
        X = px; Y = py; Z = pz;
    } else {
        const float* M = rotations + 9 * ridx;
        const float ox = observer[0], oy = observer[1], oz = observer[2];
        const float qx = px - ox, qy = py - oy, qz = pz - oz;
        float rx = M[0] * qx + M[1] * qy + M[2] * qz;
        float ry = M[3] * qx + M[4] * qy + M[5] * qz;
        float rz = M[6] * qx + M[7] * qy + M[8] * qz + floorf(r_center / maxd) * maxd;
        const float vx = vel[3 * i], vy = vel[3 * i + 1], vz = vel[3 * i + 2];
        const float vrx = M[0] * vx + M[1] * vy + M[2] * vz;
        const float vry = M[3] * vx + M[4] * vy + M[5] * vz;
        const float vrz = M[6] * vx + M[7] * vy + M[8] * vz;
        const float dx = rx - ox, dy = ry - oy, dz = rz - oz;
        const float dist  = sqrtf(dx * dx + dy * dy + dz * dz);
        const float a_tgt = 1.0f / (1.0f + dist / 3000.0f);
        const float ac    = sqrtf(t * a_tgt);
        const float drift = (a_tgt * sqrtf(a_tgt) - t * sqrtf(t)) / (1.5f * sqrtf(ac));
        X = rx + drift * vrx + ox;
        Y = ry + drift * vry + oy;
        Z = rz + drift * vrz + oz;
    }
    if (!(Z >= r_center - width * 0.5f && Z < r_center + width * 0.5f)) return;

    const float scale = (float)res / box;
    const float gx = X * scale, gy = Y * scale;
    const float fgx = floorf(gx), fgy = floorf(gy);
    scatter_direct(out, res, wrap_idx((int)fgx, res), wrap_idx((int)fgy, res),
                   gx - fgx, gy - fgy);
}

extern "C" void kernel_launch(void* const* d_in, const int* in_sizes, int n_in,
                              void* d_out, int out_size, void* d_ws, size_t ws_size,
                              hipStream_t stream) {
    const float* pos   = (const float*)d_in[0];
    const float* velv  = (const float*)d_in[1];
    const float* rot   = (const float*)d_in[2];
    const float* obs   = (const float*)d_in[3];
    const float* rc    = (const float*)d_in[4];
    const float* dw    = (const float*)d_in[5];
    const float* t     = (const float*)d_in[6];
    const float* maxd  = (const float*)d_in[7];
    const float* box   = (const float*)d_in[8];
    const int*   shell = (const int*)d_in[9];
    const int*   ridx  = (const int*)d_in[10];
    float* out = (float*)d_out;

    const int n   = in_sizes[0] / 3;
    const int res = (int)llround(sqrt((double)out_size));

    // output is poisoned with 0xAA before every timed launch — zero it.
    hipMemsetAsync(out, 0, (size_t)out_size * sizeof(float), stream);

    const int tiles = res / TSZ;
    const int nt2 = tiles * tiles;
    const size_t rec_bytes = (size_t)NBKT * NBLK * SLOTS * sizeof(unsigned);
    const size_t cnt_bytes = (size_t)NBLK * NBKT;   // u8 counts
    const bool pow2 = res > 0 && (res & (res - 1)) == 0;

    if (!pow2 || res % TSZ != 0 || nt2 > NBKT ||
        (long long)res * res != (long long)out_size ||
        ws_size < rec_bytes + cnt_bytes) {
        tp_direct<<<(n + 255) / 256, 256, 0, stream>>>(
            pos, velv, rot, obs, rc, dw, t, maxd, box, shell, ridx, out, res, n);
        return;
    }

    unsigned* grec = (unsigned*)d_ws;
    unsigned char* cnts = (unsigned char*)d_ws + rec_bytes;

    const int per_round = NBLK * NTH * VEC * NSUB;
    const int rounds = (n + per_round - 1) / per_round;
    tp_bin<<<NBLK, NTH, 0, stream>>>(
        pos, velv, rot, obs, rc, dw, t, maxd, box, shell, ridx,
        cnts, grec, out, res, tiles, n, rounds);

    tp_paint<<<nt2, 1024, 0, stream>>>(cnts, grec, out, res, tiles);
}

// Round 4
// 289.159 us; speedup vs baseline: 1.0213x; 1.0213x over previous
//
#include <hip/hip_runtime.h>
#include <cmath>

// TelephotoInterp: rotate+shift+drift 8.4M particles, CIC-paint z-slab onto
// res x res (2048^2) f32 grid.
//
// Round-10: rounds 7-9 falsified occupancy / LDS-chain / global-atomic
// theories: tp_bin pinned at ~90us, VALUBusy ~23%, one chunk per ~6200
// SIMD-cycles REGARDLESS of resident waves (2.5 vs 6 per SIMD). Issue work
// is only ~1900 cyc/chunk -> waves are collectively stalled: the barrier-
// phased rounds put every wave on the device into phase 1 simultaneously
// (load burst, memory latency spikes), then drain vmcnt(0) together, then
// idle together through phase 2. Convoy = famine/flood; occupancy can't help
// because all waves stall at the same instants.
// Fix: wave-autonomous binning, ZERO barriers in the kernel. Each wave owns
// private LDS buckets (256 x DEPTH=18, ~20KB/wave, 2 blocks/CU); flush when
// a bucket hits 16: the lane whose ds_add_rtn returned 15 is the unique
// owner and writes the 64B chunk to deterministic arena [bucket][wave][16].
// No global atomics, no descriptors, no phases. Overshoot (>=DEPTH) and
// arena overflow (2nd flush / residue when full, ~0.8% of bucket-waves)
// take the correct scatter_direct fallback. Residues drain at kernel end.
// Paint: linear coalesced scan of [bucket][wave][16] with u8 counts (r9).

#define TSZ    128        // paint tile edge (cells)
#define NBKT   256        // buckets (= max tiles^2 in fast path, tiles<=16)
#define DEPTH  18         // per-wave LDS slots per bucket (flush@16, +2 room)
#define SLOTS  16         // arena records per (bucket,wave)
#define NTH    256        // block size (4 waves)
#define WPB    4          // waves per block
#define NBLK   480        // grid: 1920 waves, ~2 blocks/CU (LDS-capped)
#define NWAVES (NBLK*WPB)
#define VEC    4          // particles per thread per chunk

__device__ __forceinline__ float fast_rcp(float x)  { return __builtin_amdgcn_rcpf(x); }
__device__ __forceinline__ float fast_sqrt(float x) { return __builtin_amdgcn_sqrtf(x); }

__device__ __forceinline__ int wrap_idx(int v, int res) {   // generic (fallback path)
    v += (v < 0) ? res : 0;
    v += (v < 0) ? res : 0;
    v += (v < 0) ? res : 0;
    v -= (v >= res) ? res : 0;
    v -= (v >= res) ? res : 0;
    v -= (v >= res) ? res : 0;
    if (v < 0 || v >= res) { v %= res; if (v < 0) v += res; }  // safety net
    return v;
}

__device__ __forceinline__ void scatter_direct(float* __restrict__ out, int res,
                                               int gx0, int gy0, float fx, float fy) {
    int gx1 = gx0 + 1; if (gx1 >= res) gx1 = 0;
    int gy1 = gy0 + 1; if (gy1 >= res) gy1 = 0;
    atomicAdd(&out[gx0 * res + gy0], (1.0f - fx) * (1.0f - fy));
    atomicAdd(&out[gx1 * res + gy0], fx * (1.0f - fy));
    atomicAdd(&out[gx0 * res + gy1], (1.0f - fx) * fy);
    atomicAdd(&out[gx1 * res + gy1], fx * fy);
}

// rec = lx7<<25 | ly7<<18 | qx9<<9 | qy9
__device__ __forceinline__ void rec_decode(unsigned rec, int b, int tiles,
                                           int& gx, int& gy, float& fx, float& fy) {
    int tx = b / tiles, ty = b - tx * tiles;   // rare path only
    gx = (tx << 7) + (int)(rec >> 25);
    gy = (ty << 7) + (int)((rec >> 18) & 127u);
    fx = (float)((rec >> 9) & 511u) * (1.0f / 512.0f);
    fy = (float)(rec & 511u) * (1.0f / 512.0f);
}

// uniforms for the per-particle fast path
struct Uni {
    float m00, m01, m02, m10, m11, m12, m20, m21, m22;
    float ox, oy, oz, shift;
    float r_lo, r_hi, t, gp_t, scale;
    int   resm1, res, tiles;
    bool  inside;
};

// per-particle result (registers only; callers fully unrolled)
struct PR {
    unsigned rec, st;
    int ix0, iy0;
    float fx, fy;
    bool val;
};

// ---------------- per-particle compute (branch-free, no side effects) ----
__device__ __forceinline__ PR tp_compute(
    const Uni& u, unsigned dummy,
    float px, float py, float pz, float vx, float vy, float vz)
{
    float X, Y, Z;
    if (u.inside) {
        X = px; Y = py; Z = pz;
    } else {
        const float qx_ = px - u.ox, qy_ = py - u.oy, qz_ = pz - u.oz;
        float rx = u.m00 * qx_ + u.m01 * qy_ + u.m02 * qz_;
        float ry = u.m10 * qx_ + u.m11 * qy_ + u.m12 * qz_;
        float rz = u.m20 * qx_ + u.m21 * qy_ + u.m22 * qz_ + u.shift;

        const float vrx = u.m00 * vx + u.m01 * vy + u.m02 * vz;
        const float vry = u.m10 * vx + u.m11 * vy + u.m12 * vz;
        const float vrz = u.m20 * vx + u.m21 * vy + u.m22 * vz;

        const float dx = rx - u.ox, dy = ry - u.oy, dz = rz - u.oz;
        const float dist  = fast_sqrt(dx * dx + dy * dy + dz * dz);
        const float a_tgt = fast_rcp(1.0f + dist * (1.0f / 3000.0f));
        const float ac    = fast_sqrt(u.t * a_tgt);
        const float gp_a  = a_tgt * fast_sqrt(a_tgt);          // a^1.5
        const float drift = (gp_a - u.gp_t) * fast_rcp(1.5f * fast_sqrt(ac));

        X = rx + drift * vrx + u.ox;
        Y = ry + drift * vry + u.oy;
        Z = rz + drift * vrz + u.oz;
    }
    PR o;
    o.val = (Z >= u.r_lo && Z < u.r_hi);

    // all of the below is finite/safe even for rejected particles
    const float gx = X * u.scale, gy = Y * u.scale;
    const float fgx = floorf(gx), fgy = floorf(gy);
    o.fx = gx - fgx; o.fy = gy - fgy;
    o.ix0 = ((int)fgx) & u.resm1;   // exact mod for pow2 res
    o.iy0 = ((int)fgy) & u.resm1;
    const unsigned st = (unsigned)((o.ix0 >> 7) * u.tiles + (o.iy0 >> 7));
    o.st = o.val ? st : dummy;      // invalid lanes -> per-lane dummy bucket

    unsigned qx = (unsigned)(o.fx * 512.0f + 0.5f); if (qx > 511u) qx = 511u;
    unsigned qy = (unsigned)(o.fy * 512.0f + 0.5f); if (qy > 511u) qy = 511u;
    o.rec = ((unsigned)(o.ix0 & 127) << 25) | ((unsigned)(o.iy0 & 127) << 18)
          | (qx << 9) | qy;
    return o;
}

__device__ __forceinline__ void tp_finish(
    const Uni& u, const PR& o, unsigned p,
    unsigned* __restrict__ fill, unsigned* __restrict__ buf,
    float* __restrict__ out)
{
    if (!o.val) return;
    if (p < DEPTH) buf[o.st * DEPTH + p] = o.rec;
    else { atomicSub(&fill[o.st], 1u); scatter_direct(out, u.res, o.ix0, o.iy0, o.fx, o.fy); }
}

// lane whose atomic returned 15 is the unique flush owner for its bucket.
// Runs after ALL finishes of the chunk (so fill is settled). Wave-lockstep
// makes this race-free: no other wave touches this wave's buckets.
__device__ __forceinline__ void flush_if(
    const Uni& u, const PR& o, unsigned p, unsigned w,
    unsigned* __restrict__ fill, unsigned* __restrict__ buf,
    unsigned char* __restrict__ cid,
    unsigned* __restrict__ grec, float* __restrict__ out)
{
    if (o.val && p == 15u) {
        const unsigned b = o.st;
        const unsigned c = fill[b];          // 16..DEPTH, post-batch
        const unsigned ci = cid[b];
        if (ci == 0u) {                      // arena chunk available
            const size_t dst = ((size_t)b * NWAVES + w) * SLOTS;
            #pragma unroll
            for (int i = 0; i < 16; i += 4) {
                uint4 v;
                v.x = buf[b * DEPTH + i];
                v.y = buf[b * DEPTH + i + 1];
                v.z = buf[b * DEPTH + i + 2];
                v.w = buf[b * DEPTH + i + 3];
                *(uint4*)(grec + dst + i) = v;
            }
        } else {                             // arena full: correct fallback
            for (int i = 0; i < 16; ++i) {
                int gx0, gy0; float ffx, ffy;
                rec_decode(buf[b * DEPTH + i], (int)b, u.tiles, gx0, gy0, ffx, ffy);
                scatter_direct(out, u.res, gx0, gy0, ffx, ffy);
            }
        }
        cid[b] = (unsigned char)(ci + 1u);
        const unsigned resid = c - 16u;      // <= DEPTH-16
        for (unsigned j = 0; j < resid; ++j)
            buf[b * DEPTH + j] = buf[b * DEPTH + 16u + j];
        fill[b] = resid;
    }
}

// ---------------- K1: transform + wave-autonomous bin (no barriers) -------
__global__ __launch_bounds__(NTH) void tp_bin(
    const float* __restrict__ pos, const float* __restrict__ vel,
    const float* __restrict__ rotations, const float* __restrict__ observer,
    const float* __restrict__ r_centers, const float* __restrict__ widths,
    const float* __restrict__ t_p, const float* __restrict__ maxd_p,
    const float* __restrict__ box_p, const int* __restrict__ shell_p,
    const int* __restrict__ ridx_p,
    unsigned char* __restrict__ cnts, unsigned* __restrict__ grec,
    float* __restrict__ out, int res, int tiles, int n, int cpw)
{
    __shared__ unsigned fillS[WPB][NBKT + 64];   // +64 per-lane dummy buckets
    __shared__ unsigned bufS[WPB][NBKT * DEPTH];
    __shared__ unsigned char cidS[WPB][NBKT];

    const int tid  = threadIdx.x;
    const int wv   = tid >> 6;
    const int lane = tid & 63;
    unsigned* __restrict__ fill = fillS[wv];
    unsigned* __restrict__ buf  = bufS[wv];
    unsigned char* __restrict__ cid = cidS[wv];

    // per-wave init; same-wave LDS ordering needs no barrier
    for (int b = lane; b < NBKT + 64; b += 64) fill[b] = 0;
    for (int b = lane; b < NBKT; b += 64) cid[b] = 0;

    Uni u;
    {
        const int   shell    = shell_p[0];
        const float r_center = r_centers[shell];
        const float width    = widths[shell];
        const float maxd     = maxd_p[0];
        const float box      = box_p[0];
        u.t      = t_p[0];
        u.inside = (r_center + width * 0.5f) <= maxd;
        int ridx = ridx_p[0] % 47; if (ridx < 0) ridx += 47;
        const float* M = rotations + 9 * ridx;
        u.m00 = M[0]; u.m01 = M[1]; u.m02 = M[2];
        u.m10 = M[3]; u.m11 = M[4]; u.m12 = M[5];
        u.m20 = M[6]; u.m21 = M[7]; u.m22 = M[8];
        u.ox = observer[0]; u.oy = observer[1]; u.oz = observer[2];
        u.shift = floorf(r_center / maxd) * maxd;
        u.r_lo = r_center - width * 0.5f;
        u.r_hi = r_center + width * 0.5f;
        u.gp_t = u.t * sqrtf(u.t);
        u.scale = (float)res / box;
        u.resm1 = res - 1; u.res = res; u.tiles = tiles;
    }

    const unsigned w = (unsigned)(blockIdx.x * WPB + wv);
    const unsigned dummy = (unsigned)(NBKT + lane);
    const float4* __restrict__ pos4 = (const float4*)pos;
    const float4* __restrict__ vel4 = (const float4*)vel;

    for (int k = 0; k < cpw; ++k) {
        const int base = (((k * NWAVES + (int)w) * 64) + lane) * VEC;
        PR pr[4];
        if (base + VEC <= n) {
            const int q = base * 3 / 4;   // float4 index (base*3 divisible by 4)
            const float4 a = pos4[q], b = pos4[q + 1], c = pos4[q + 2];
            if (u.inside) {
                pr[0] = tp_compute(u, dummy, a.x, a.y, a.z, 0, 0, 0);
                pr[1] = tp_compute(u, dummy, a.w, b.x, b.y, 0, 0, 0);
                pr[2] = tp_compute(u, dummy, b.z, b.w, c.x, 0, 0, 0);
                pr[3] = tp_compute(u, dummy, c.y, c.z, c.w, 0, 0, 0);
            } else {
                const float4 d = vel4[q], e = vel4[q + 1], f = vel4[q + 2];
                pr[0] = tp_compute(u, dummy, a.x, a.y, a.z, d.x, d.y, d.z);
                pr[1] = tp_compute(u, dummy, a.w, b.x, b.y, d.w, e.x, e.y);
                pr[2] = tp_compute(u, dummy, b.z, b.w, c.x, e.z, e.w, f.x);
                pr[3] = tp_compute(u, dummy, c.y, c.z, c.w, f.y, f.z, f.w);
            }
        } else {
            #pragma unroll
            for (int j = 0; j < VEC; ++j) {
                const int i = base + j;
                const bool ok = (i >= 0) && (i < n);
                float px = 0, py = 0, pz = 0, vx = 0, vy = 0, vz = 0;
                if (ok) {
                    px = pos[3 * i]; py = pos[3 * i + 1]; pz = pos[3 * i + 2];
                    if (!u.inside) {
                        vx = vel[3 * i]; vy = vel[3 * i + 1]; vz = vel[3 * i + 2];
                    }
                }
                PR t = tp_compute(u, dummy, px, py, pz, vx, vy, vz);
                if (!ok) { t.val = false; t.st = dummy; }
                pr[j] = t;
            }
        }
        unsigned pp[4];
        #pragma unroll
        for (int j = 0; j < 4; ++j) pp[j] = atomicAdd(&fill[pr[j].st], 1u);
        #pragma unroll
        for (int j = 0; j < 4; ++j) tp_finish(u, pr[j], pp[j], fill, buf, out);
        #pragma unroll
        for (int j = 0; j < 4; ++j) flush_if(u, pr[j], pp[j], w, fill, buf, cid, grec, out);
    }

    // drain residues (fill < 16 each) + write exact per-(wave,bucket) counts
    #pragma unroll
    for (int j = 0; j < NBKT / 64; ++j) {
        const int b = lane + j * 64;
        const unsigned c = fill[b];
        const unsigned ci = cid[b];
        unsigned char cb;
        if (ci == 0u) {
            cb = (unsigned char)c;
            const size_t dst = ((size_t)b * NWAVES + w) * SLOTS;
            for (unsigned i = 0; i < c; ++i) grec[dst + i] = buf[b * DEPTH + i];
        } else {
            cb = (unsigned char)SLOTS;   // one full chunk in arena; resid -> fallback
            for (unsigned i = 0; i < c; ++i) {
                int gx0, gy0; float ffx, ffy;
                rec_decode(buf[b * DEPTH + i], b, u.tiles, gx0, gy0, ffx, ffy);
                scatter_direct(out, u.res, gx0, gy0, ffx, ffy);
            }
        }
        cnts[(size_t)w * NBKT + b] = cb;
    }
}

// ---------------- K2: paint (one 128-tile per block, quad u64 accumulate) ----
// 4 parity-staggered quad grids; a record at (li,lj) hits exactly one quad:
// grid (li&1, lj&1), index (li>>1, lj>>1). u64 = 4x u16 fixed-point (2^-10):
// slot(r,s) at bits 16*(r*2+s) = weight for cell (li+r, lj+s). Exact while
// each cell's weight-sum < 64 (actual max ~12).
// Record read: linear coalesced scan of this bucket's NWAVES*SLOTS arena
// region; slot validity via per-wave u8 counts preloaded in LDS.
__global__ __launch_bounds__(1024) void tp_paint(
    const unsigned char* __restrict__ cnts, const unsigned* __restrict__ grec,
    float* __restrict__ out, int res, int tiles)
{
    __shared__ unsigned long long quad[4][64 * 64];   // 128 KB
    __shared__ unsigned char cs[NWAVES];              // per-source-wave counts
    const int b = blockIdx.x;
    const int tx = b / tiles, ty = b - tx * tiles;

    for (int c = threadIdx.x; c < 4 * 64 * 64; c += blockDim.x)
        quad[c >> 12][c & 4095] = 0ull;
    for (int i = threadIdx.x; i < NWAVES; i += blockDim.x)
        cs[i] = cnts[(size_t)i * NBKT + b];
    __syncthreads();

    const unsigned* __restrict__ rr = grec + (size_t)b * NWAVES * SLOTS;
    const int total = NWAVES * SLOTS;
    for (int idx = threadIdx.x; idx < total; idx += blockDim.x) {
        const unsigned p = rr[idx];                    // coalesced stream
        if ((idx & (SLOTS - 1)) < (int)cs[idx >> 4]) { // SLOTS == 16
            const int li = (int)(p >> 25);
            const int lj = (int)((p >> 18) & 127u);
            const unsigned qx = (p >> 9) & 511u;
            const unsigned qy = p & 511u;
            const unsigned ax = 512u - qx, ay = 512u - qy;
            const unsigned long long w00 = (ax * ay + 128u) >> 8;
            const unsigned long long w01 = (ax * qy + 128u) >> 8;
            const unsigned long long w10 = (qx * ay + 128u) >> 8;
            const unsigned long long w11 = (qx * qy + 128u) >> 8;
            const unsigned long long pk = w00 | (w01 << 16) | (w10 << 32) | (w11 << 48);
            const int g = ((li & 1) << 1) | (lj & 1);
            atomicAdd(&quad[g][(li >> 1) * 64 + (lj >> 1)], pk);
        }
    }
    __syncthreads();

    for (int c = threadIdx.x; c < (TSZ + 1) * (TSZ + 1); c += blockDim.x) {
        const int i = c / (TSZ + 1), j = c - i * (TSZ + 1);
        unsigned acc = 0;
        #pragma unroll
        for (int r = 0; r < 2; ++r) {
            const int ii = i - r;
            if (ii < 0 || ii > TSZ - 1) continue;
            #pragma unroll
            for (int s = 0; s < 2; ++s) {
                const int jj = j - s;
                if (jj < 0 || jj > TSZ - 1) continue;
                const int g = ((ii & 1) << 1) | (jj & 1);
                const unsigned long long v = quad[g][(ii >> 1) * 64 + (jj >> 1)];
                acc += (unsigned)((v >> (16 * (r * 2 + s))) & 0xffffull);
            }
        }
        const float val = (float)acc * (1.0f / 1024.0f);
        int gx = tx * TSZ + i; if (gx >= res) gx -= res;
        int gy = ty * TSZ + j; if (gy >= res) gy -= res;
        float* dst = &out[gx * res + gy];
        if (i == 0 || j == 0 || i == TSZ || j == TSZ) {
            if (val != 0.0f) atomicAdd(dst, val);   // halo-shared frame cells
        } else {
            *dst += val;   // exclusive writer; += keeps fallback atomics
        }
    }
}

// ---------------- fallback direct kernel (non-pow2 / odd res / small ws) ----
__global__ __launch_bounds__(256) void tp_direct(
    const float* __restrict__ pos, const float* __restrict__ vel,
    const float* __restrict__ rotations, const float* __restrict__ observer,
    const float* __restrict__ r_centers, const float* __restrict__ widths,
    const float* __restrict__ t_p, const float* __restrict__ maxd_p,
    const float* __restrict__ box_p, const int* __restrict__ shell_p,
    const int* __restrict__ ridx_p, float* __restrict__ out, int res, int n)
{
    int i = blockIdx.x * blockDim.x + threadIdx.x;
    if (i >= n) return;
    const int   shell    = shell_p[0];
    const float r_center = r_centers[shell];
    const float width    = widths[shell];
    const float maxd     = maxd_p[0];
    const float box      = box_p[0];
    const float t        = t_p[0];
    const bool  inside   = (r_center + width * 0.5f) <= maxd;
    int ridx = ridx_p[0] % 47; if (ridx < 0) ridx += 47;

    float px = pos[3 * i], py = pos[3 * i + 1], pz = pos[3 * i + 2];
    float X, Y, Z;
    if (inside) {
        X = px; Y = py; Z = pz;
    } else {
        const float* M = rotations + 9 * ridx;
        const float ox = observer[0], oy = observer[1], oz = observer[2];
        const float qx = px - ox, qy = py - oy, qz = pz - oz;
        float rx = M[0] * qx + M[1] * qy + M[2] * qz;
        float ry = M[3] * qx + M[4] * qy + M[5] * qz;
        float rz = M[6] * qx + M[7] * qy + M[8] * qz + floorf(r_center / maxd) * maxd;
        const float vx = vel[3 * i], vy = vel[3 * i + 1], vz = vel[3 * i + 2];
        const float vrx = M[0] * vx + M[1] * vy + M[2] * vz;
        const float vry = M[3] * vx + M[4] * vy + M[5] * vz;
        const float vrz = M[6] * vx + M[7] * vy + M[8] * vz;
        const float dx = rx - ox, dy = ry - oy, dz = rz - oz;
        const float dist  = sqrtf(dx * dx + dy * dy + dz * dz);
        const float a_tgt = 1.0f / (1.0f + dist / 3000.0f);
        const float ac    = sqrtf(t * a_tgt);
        const float drift = (a_tgt * sqrtf(a_tgt) - t * sqrtf(t)) / (1.5f * sqrtf(ac));
        X = rx + drift * vrx + ox;
        Y = ry + drift * vry + oy;
        Z = rz + drift * vrz + oz;
    }
    if (!(Z >= r_center - width * 0.5f && Z < r_center + width * 0.5f)) return;

    const float scale = (float)res / box;
    const float gx = X * scale, gy = Y * scale;
    const float fgx = floorf(gx), fgy = floorf(gy);
    scatter_direct(out, res, wrap_idx((int)fgx, res), wrap_idx((int)fgy, res),
                   gx - fgx, gy - fgy);
}

extern "C" void kernel_launch(void* const* d_in, const int* in_sizes, int n_in,
                              void* d_out, int out_size, void* d_ws, size_t ws_size,
                              hipStream_t stream) {
    const float* pos   = (const float*)d_in[0];
    const float* velv  = (const float*)d_in[1];
    const float* rot   = (const float*)d_in[2];
    const float* obs   = (const float*)d_in[3];
    const float* rc    = (const float*)d_in[4];
    const float* dw    = (const float*)d_in[5];
    const float* t     = (const float*)d_in[6];
    const float* maxd  = (const float*)d_in[7];
    const float* box   = (const float*)d_in[8];
    const int*   shell = (const int*)d_in[9];
    const int*   ridx  = (const int*)d_in[10];
    float* out = (float*)d_out;

    const int n   = in_sizes[0] / 3;
    const int res = (int)llround(sqrt((double)out_size));

    // output is poisoned with 0xAA before every timed launch — zero it.
    hipMemsetAsync(out, 0, (size_t)out_size * sizeof(float), stream);

    const int tiles = res / TSZ;
    const int nt2 = tiles * tiles;
    const size_t rec_bytes = (size_t)NBKT * NWAVES * SLOTS * sizeof(unsigned);
    const size_t cnt_bytes = (size_t)NWAVES * NBKT;   // u8 counts
    const bool pow2 = res > 0 && (res & (res - 1)) == 0;

    if (!pow2 || res % TSZ != 0 || nt2 > NBKT ||
        (long long)res * res != (long long)out_size ||
        ws_size < rec_bytes + cnt_bytes) {
        tp_direct<<<(n + 255) / 256, 256, 0, stream>>>(
            pos, velv, rot, obs, rc, dw, t, maxd, box, shell, ridx, out, res, n);
        return;
    }

    unsigned* grec = (unsigned*)d_ws;
    unsigned char* cnts = (unsigned char*)d_ws + rec_bytes;

    const int per_sweep = NWAVES * 64 * VEC;             // particles per chunk sweep
    const int cpw = (n + per_sweep - 1) / per_sweep;     // chunks per wave
    tp_bin<<<NBLK, NTH, 0, stream>>>(
        pos, velv, rot, obs, rc, dw, t, maxd, box, shell, ridx,
        cnts, grec, out, res, tiles, n, cpw);

    tp_paint<<<nt2, 1024, 0, stream>>>(cnts, grec, out, res, tiles);
}